// Round 2
// baseline (431.235 us; speedup 1.0000x reference)
//
#include <hip/hip_runtime.h>
#include <hip/hip_bf16.h>

typedef unsigned short u16;
typedef unsigned int   u32;
typedef short  short8 __attribute__((ext_vector_type(8)));
typedef float  f32x4  __attribute__((ext_vector_type(4)));

#define NB   65536
#define ROWS 16
#define XP   136
#define OFF1 ((size_t)NB * 128)
#define OFF2 (OFF1 + (size_t)NB * 4)

__device__ __forceinline__ u16 f2bf(float f) {
  union { float f; u32 u; } v; v.f = f;
  return (u16)((v.u + 0x7FFFu + ((v.u >> 16) & 1u)) >> 16);
}
__device__ __forceinline__ float bf2f(u32 bits16) {
  union { u32 u; float f; } v; v.u = bits16 << 16; return v.f;
}
__device__ __forceinline__ u32 pk2(float a, float b) {
  return (u32)f2bf(a) | ((u32)f2bf(b) << 16);
}
__device__ __forceinline__ float red16(float v) {
  v += __shfl_xor(v, 1); v += __shfl_xor(v, 2);
  v += __shfl_xor(v, 4); v += __shfl_xor(v, 8);
  return v;
}

// ---------------- weight pre-pack: 10 x [128][128] fp32 -> bf16 MFMA-B-fragment order
// packed[t]: t = w*16384 + nt*2048 + kt*512 + lane*8 + j
//   holds W_w[kt*32 + (lane>>4)*8 + j][nt*16 + (lane&15)]
__global__ void pack_w(const float* __restrict__ proj_w,
                       const float* __restrict__ in_proj_w,
                       const float* __restrict__ out_w,
                       const float* __restrict__ gate_w,
                       u16* __restrict__ wp) {
  int t = blockIdx.x * 256 + threadIdx.x;
  if (t >= 10 * 16384) return;
  int w = t >> 14, i = t & 16383;
  int nt = i >> 11, kt = (i >> 9) & 3, ln = (i >> 3) & 63, j = i & 7;
  int k = kt * 32 + ((ln >> 4) << 3) + j;
  int n = (nt << 4) + (ln & 15);
  float v;
  if (w < 4)       v = proj_w[((size_t)w << 14) + (k << 7) + n];
  else if (w < 7)  v = in_proj_w[k * 384 + ((w - 4) << 7) + n];
  else if (w == 7) v = out_w[(k << 7) + n];
  else             v = gate_w[(((w - 8) << 7) + k) * 128 + n];
  wp[t] = f2bf(v);
}

__device__ __forceinline__ short8 bfrag(const u16* __restrict__ wp, int w, int nt, int kt, int lane) {
  return *(const short8*)(wp + ((size_t)w << 14) + (size_t)((((nt << 2) + kt) << 6) + lane) * 8);
}

struct AF { short8 a[4]; };
__device__ __forceinline__ AF loadA(const u16 (*Ab)[XP], int row, int lgrp) {
  AF r;
  #pragma unroll
  for (int kt = 0; kt < 4; ++kt)
    r.a[kt] = *(const short8*)&Ab[row][kt * 32 + (lgrp << 3)];
  return r;
}
__device__ __forceinline__ f32x4 mmK128(const AF& A, const u16* __restrict__ wp, int w,
                                        int ntg, int lane, float bias) {
  f32x4 acc = {bias, bias, bias, bias};
  #pragma unroll
  for (int kt = 0; kt < 4; ++kt)
    acc = __builtin_amdgcn_mfma_f32_16x16x32_bf16(A.a[kt], bfrag(wp, w, ntg, kt, lane), acc, 0, 0, 0);
  return acc;
}

__global__ __launch_bounds__(128, 3) void fused_k(
    const float* __restrict__ h0, const float* __restrict__ h1,
    const float* __restrict__ h2, const float* __restrict__ h3,
    const u16* __restrict__ wp,
    const float* __restrict__ proj_b, const float* __restrict__ ctx_w,
    const float* __restrict__ in_proj_b, const float* __restrict__ out_b,
    const float* __restrict__ gate_b, const float* __restrict__ pool_w,
    const float* __restrict__ ln_g, const float* __restrict__ ln_b,
    float* __restrict__ out) {
  __shared__ __align__(16) u16 xls[4][ROWS][XP];  // h -> x -> normalized fused
  __shared__ __align__(16) u16 aux[ROWS][XP];     // context -> o
  __shared__ __align__(16) u16 aob[ROWS][XP];     // attn_out
  __shared__ float lgt[4][2][ROWS];               // ctx logit partials -> cw
  __shared__ float scf[4][ROWS][4];               // scores -> attn
  __shared__ float lnr[ROWS][2][2];               // LN partials
  __shared__ float lgp2[4][ROWS][2];              // pool logit partials -> pw

  const int tid   = threadIdx.x;
  const int lane  = tid & 63;
  const int wid   = tid >> 6;
  const int nt0   = wid << 2;
  const int r0    = blockIdx.x * ROWS;
  const int lrow  = lane & 15;
  const int lgrp  = lane >> 4;
  const int crow0 = lgrp << 2;

  const float* hp[4] = {h0, h1, h2, h3};

  // ---- phase 0: load h_s (bf16) into xls
  #pragma unroll
  for (int s = 0; s < 4; ++s) {
    const float* __restrict__ hs = hp[s];
    #pragma unroll
    for (int i = 0; i < 4; ++i) {
      int f4 = i * 128 + tid;
      int row = f4 >> 5, c0 = (f4 & 31) << 2;
      const float4 v = *(const float4*)(hs + ((size_t)(r0 + row) << 7) + c0);
      *(uint2*)&xls[s][row][c0] = make_uint2(pk2(v.x, v.y), pk2(v.z, v.w));
    }
  }
  __syncthreads();
  AF Ah[4];
  #pragma unroll
  for (int s = 0; s < 4; ++s) Ah[s] = loadA(xls[s], lrow, lgrp);
  __syncthreads();

  // ---- phase 1: proj GEMMs (in-place h->x) + ctx logit partials
  #pragma unroll
  for (int s = 0; s < 4; ++s) {
    float lp[4] = {0.f, 0.f, 0.f, 0.f};
    #pragma unroll
    for (int nt = 0; nt < 4; ++nt) {
      int ntg = nt0 + nt, n = (ntg << 4) + lrow;
      f32x4 acc = mmK128(Ah[s], wp, s, ntg, lane, proj_b[(s << 7) + n]);
      float cwn = ctx_w[n];
      #pragma unroll
      for (int j = 0; j < 4; ++j) {
        lp[j] += acc[j] * cwn;
        xls[s][crow0 + j][n] = f2bf(acc[j]);
      }
    }
    #pragma unroll
    for (int j = 0; j < 4; ++j) lp[j] = red16(lp[j]);
    if (lrow == 0) {
      #pragma unroll
      for (int j = 0; j < 4; ++j) lgt[s][wid][crow0 + j] = lp[j];
    }
  }
  __syncthreads();

  // ---- phase 2: ctx softmax over s (ctx_b cancels)
  if (tid < ROWS) {
    float l0 = lgt[0][0][tid] + lgt[0][1][tid];
    float l1 = lgt[1][0][tid] + lgt[1][1][tid];
    float l2 = lgt[2][0][tid] + lgt[2][1][tid];
    float l3 = lgt[3][0][tid] + lgt[3][1][tid];
    float mx = fmaxf(fmaxf(l0, l1), fmaxf(l2, l3));
    float e0 = __expf(l0 - mx), e1 = __expf(l1 - mx), e2 = __expf(l2 - mx), e3 = __expf(l3 - mx);
    float inv = 1.f / (e0 + e1 + e2 + e3);
    lgt[0][0][tid] = e0 * inv; lgt[1][0][tid] = e1 * inv;
    lgt[2][0][tid] = e2 * inv; lgt[3][0][tid] = e3 * inv;
  }
  __syncthreads();

  // ---- phase 3: context = sum_s cw[s]*x_s -> aux
  #pragma unroll
  for (int i = 0; i < 4; ++i) {
    int e4 = i * 128 + tid;
    int row = e4 >> 5, c0 = (e4 & 31) << 2;
    float a0 = 0, a1 = 0, a2 = 0, a3 = 0;
    #pragma unroll
    for (int s = 0; s < 4; ++s) {
      float cw = lgt[s][0][row];
      uint2 d = *(const uint2*)&xls[s][row][c0];
      a0 += cw * bf2f(d.x & 0xffff); a1 += cw * bf2f(d.x >> 16);
      a2 += cw * bf2f(d.y & 0xffff); a3 += cw * bf2f(d.y >> 16);
    }
    *(uint2*)&aux[row][c0] = make_uint2(pk2(a0, a1), pk2(a2, a3));
  }
  __syncthreads();

  // ---- phase 4: q = context @ wq + bq (kept in regs) ; load x A-frags
  AF Ax[4];
  #pragma unroll
  for (int s = 0; s < 4; ++s) Ax[s] = loadA(xls[s], lrow, lgrp);
  float qf[4][4];
  {
    AF Ac = loadA(aux, lrow, lgrp);
    #pragma unroll
    for (int nt = 0; nt < 4; ++nt) {
      int ntg = nt0 + nt, n = (ntg << 4) + lrow;
      f32x4 acc = mmK128(Ac, wp, 4, ntg, lane, in_proj_b[n]);
      #pragma unroll
      for (int j = 0; j < 4; ++j) qf[nt][j] = acc[j];
    }
  }

  // ---- phase 5: K GEMM (s-inner, B-frag shared) + scores
  {
    float sc[4][4][2] = {};
    #pragma unroll
    for (int nt = 0; nt < 4; ++nt) {
      int ntg = nt0 + nt, n = (ntg << 4) + lrow;
      const int hh = (ntg >> 1) & 1;
      float bk = in_proj_b[128 + n];
      f32x4 ak[4];
      #pragma unroll
      for (int s = 0; s < 4; ++s) ak[s] = (f32x4){bk, bk, bk, bk};
      #pragma unroll
      for (int kt = 0; kt < 4; ++kt) {
        short8 bf = bfrag(wp, 5, ntg, kt, lane);
        #pragma unroll
        for (int s = 0; s < 4; ++s)
          ak[s] = __builtin_amdgcn_mfma_f32_16x16x32_bf16(Ax[s].a[kt], bf, ak[s], 0, 0, 0);
      }
      #pragma unroll
      for (int s = 0; s < 4; ++s)
        #pragma unroll
        for (int j = 0; j < 4; ++j)
          sc[s][j][hh] += ak[s][j] * qf[nt][j];
    }
    #pragma unroll
    for (int s = 0; s < 4; ++s)
      #pragma unroll
      for (int j = 0; j < 4; ++j)
        #pragma unroll
        for (int hh = 0; hh < 2; ++hh)
          sc[s][j][hh] = red16(sc[s][j][hh]);
    #pragma unroll
    for (int s = 0; s < 4; ++s)
      #pragma unroll
      for (int hh = 0; hh < 2; ++hh) {
        int h = (wid << 1) + hh;
        if (lrow == h) {
          #pragma unroll
          for (int j = 0; j < 4; ++j) scf[s][crow0 + j][h] = sc[s][j][hh];
        }
      }
  }
  __syncthreads();

  // ---- phase 5b: attn softmax over s
  if (tid < 64) {
    int row = tid >> 2, h = tid & 3;
    const float scale = 0.17677669529663687f;  // 1/sqrt(32)
    float l0 = scf[0][row][h] * scale, l1 = scf[1][row][h] * scale;
    float l2 = scf[2][row][h] * scale, l3 = scf[3][row][h] * scale;
    float mx = fmaxf(fmaxf(l0, l1), fmaxf(l2, l3));
    float e0 = __expf(l0 - mx), e1 = __expf(l1 - mx), e2 = __expf(l2 - mx), e3 = __expf(l3 - mx);
    float inv = 1.f / (e0 + e1 + e2 + e3);
    scf[0][row][h] = e0 * inv; scf[1][row][h] = e1 * inv;
    scf[2][row][h] = e2 * inv; scf[3][row][h] = e3 * inv;
  }
  __syncthreads();
  if (tid < 64) {
    int row = tid >> 2, s = tid & 3;
    float m = 0.25f * (scf[s][row][0] + scf[s][row][1] + scf[s][row][2] + scf[s][row][3]);
    out[OFF1 + ((size_t)(r0 + row) << 2) + s] = m;
  }

  // ---- phase 6: V GEMM (s-inner) + o = sum_s attn*v -> aux
  {
    float aw[4][4][2];
    #pragma unroll
    for (int s = 0; s < 4; ++s)
      #pragma unroll
      for (int j = 0; j < 4; ++j)
        #pragma unroll
        for (int hh = 0; hh < 2; ++hh)
          aw[s][j][hh] = scf[s][crow0 + j][(wid << 1) + hh];
    float oa[4][4] = {};
    #pragma unroll
    for (int nt = 0; nt < 4; ++nt) {
      int ntg = nt0 + nt, n = (ntg << 4) + lrow;
      const int hh = (ntg >> 1) & 1;
      float bv = in_proj_b[256 + n];
      f32x4 av[4];
      #pragma unroll
      for (int s = 0; s < 4; ++s) av[s] = (f32x4){bv, bv, bv, bv};
      #pragma unroll
      for (int kt = 0; kt < 4; ++kt) {
        short8 bf = bfrag(wp, 6, ntg, kt, lane);
        #pragma unroll
        for (int s = 0; s < 4; ++s)
          av[s] = __builtin_amdgcn_mfma_f32_16x16x32_bf16(Ax[s].a[kt], bf, av[s], 0, 0, 0);
      }
      #pragma unroll
      for (int s = 0; s < 4; ++s)
        #pragma unroll
        for (int j = 0; j < 4; ++j)
          oa[nt][j] += aw[s][j][hh] * av[s][j];
    }
    #pragma unroll
    for (int nt = 0; nt < 4; ++nt) {
      int n = ((nt0 + nt) << 4) + lrow;
      #pragma unroll
      for (int j = 0; j < 4; ++j) aux[crow0 + j][n] = f2bf(oa[nt][j]);
    }
  }
  __syncthreads();

  // ---- phase 7: attn_out = o @ out_w + out_b (regs + aob for A-frags)
  float aoreg[4][4];
  {
    AF Ao = loadA(aux, lrow, lgrp);
    #pragma unroll
    for (int nt = 0; nt < 4; ++nt) {
      int ntg = nt0 + nt, n = (ntg << 4) + lrow;
      f32x4 acc = mmK128(Ao, wp, 7, ntg, lane, out_b[n]);
      #pragma unroll
      for (int j = 0; j < 4; ++j) {
        aoreg[nt][j] = acc[j];
        aob[crow0 + j][n] = f2bf(acc[j]);
      }
    }
  }
  __syncthreads();

  // ---- phase 8: gate GEMM + sigmoid(g out) + fuse + LN + pool logit, per s
  {
    AF Aa = loadA(aob, lrow, lgrp);
    float lng[4], lnb[4], pwv[4], gbv[4];
    #pragma unroll
    for (int nt = 0; nt < 4; ++nt) {
      int n = ((nt0 + nt) << 4) + lrow;
      lng[nt] = ln_g[n]; lnb[nt] = ln_b[n]; pwv[nt] = pool_w[n]; gbv[nt] = gate_b[n];
    }
    #pragma unroll
    for (int s = 0; s < 4; ++s) {
      float fr[4][4];
      #pragma unroll
      for (int nt = 0; nt < 4; ++nt) {
        int ntg = nt0 + nt, n = (ntg << 4) + lrow;
        f32x4 acc = {gbv[nt], gbv[nt], gbv[nt], gbv[nt]};
        #pragma unroll
        for (int kt = 0; kt < 4; ++kt)
          acc = __builtin_amdgcn_mfma_f32_16x16x32_bf16(Ax[s].a[kt], bfrag(wp, 8, ntg, kt, lane), acc, 0, 0, 0);
        #pragma unroll
        for (int kt = 0; kt < 4; ++kt)
          acc = __builtin_amdgcn_mfma_f32_16x16x32_bf16(Aa.a[kt], bfrag(wp, 9, ntg, kt, lane), acc, 0, 0, 0);
        #pragma unroll
        for (int j = 0; j < 4; ++j) {
          float g = 1.f / (1.f + __expf(-acc[j]));
          out[OFF2 + (((size_t)(r0 + crow0 + j) << 2) + s) * 128 + n] = g;
          float xv = bf2f((u32)xls[s][crow0 + j][n]);
          fr[nt][j] = g * aoreg[nt][j] + (1.f - g) * xv;
        }
      }
      float sm[4] = {0, 0, 0, 0}, sq[4] = {0, 0, 0, 0};
      #pragma unroll
      for (int nt = 0; nt < 4; ++nt)
        #pragma unroll
        for (int j = 0; j < 4; ++j) {
          sm[j] += fr[nt][j];
          sq[j] += fr[nt][j] * fr[nt][j];
        }
      #pragma unroll
      for (int j = 0; j < 4; ++j) { sm[j] = red16(sm[j]); sq[j] = red16(sq[j]); }
      if (lrow == 0) {
        #pragma unroll
        for (int j = 0; j < 4; ++j) {
          lnr[crow0 + j][wid][0] = sm[j];
          lnr[crow0 + j][wid][1] = sq[j];
        }
      }
      __syncthreads();
      float pp[4] = {0, 0, 0, 0};
      #pragma unroll
      for (int j = 0; j < 4; ++j) {
        float ts = lnr[crow0 + j][0][0] + lnr[crow0 + j][1][0];
        float tq = lnr[crow0 + j][0][1] + lnr[crow0 + j][1][1];
        float mean = ts * 0.0078125f;
        float var  = tq * 0.0078125f - mean * mean;
        float rstd = rsqrtf(var + 1e-5f);
        #pragma unroll
        for (int nt = 0; nt < 4; ++nt) {
          int n = ((nt0 + nt) << 4) + lrow;
          float fn = (fr[nt][j] - mean) * rstd * lng[nt] + lnb[nt];
          xls[s][crow0 + j][n] = f2bf(fn);
          pp[j] += fn * pwv[nt];
        }
      }
      #pragma unroll
      for (int j = 0; j < 4; ++j) pp[j] = red16(pp[j]);
      if (lrow == 0) {
        #pragma unroll
        for (int j = 0; j < 4; ++j) lgp2[s][crow0 + j][wid] = pp[j];
      }
      __syncthreads();
    }
  }

  // ---- phase 9: pool softmax (pool_b cancels) + pooled output
  if (tid < ROWS) {
    float l0 = lgp2[0][tid][0] + lgp2[0][tid][1];
    float l1 = lgp2[1][tid][0] + lgp2[1][tid][1];
    float l2 = lgp2[2][tid][0] + lgp2[2][tid][1];
    float l3 = lgp2[3][tid][0] + lgp2[3][tid][1];
    float mx = fmaxf(fmaxf(l0, l1), fmaxf(l2, l3));
    float e0 = __expf(l0 - mx), e1 = __expf(l1 - mx), e2 = __expf(l2 - mx), e3 = __expf(l3 - mx);
    float inv = 1.f / (e0 + e1 + e2 + e3);
    lgp2[0][tid][0] = e0 * inv; lgp2[1][tid][0] = e1 * inv;
    lgp2[2][tid][0] = e2 * inv; lgp2[3][tid][0] = e3 * inv;
  }
  __syncthreads();
  #pragma unroll
  for (int i = 0; i < 4; ++i) {
    int e4 = i * 128 + tid;
    int row = e4 >> 5, c0 = (e4 & 31) << 2;
    float r0v = 0, r1v = 0, r2v = 0, r3v = 0;
    #pragma unroll
    for (int s = 0; s < 4; ++s) {
      float pw = lgp2[s][row][0];
      uint2 d = *(const uint2*)&xls[s][row][c0];
      r0v += pw * bf2f(d.x & 0xffff); r1v += pw * bf2f(d.x >> 16);
      r2v += pw * bf2f(d.y & 0xffff); r3v += pw * bf2f(d.y >> 16);
    }
    float4 o4; o4.x = r0v; o4.y = r1v; o4.z = r2v; o4.w = r3v;
    *(float4*)(out + ((size_t)(r0 + row) << 7) + c0) = o4;
  }
}

extern "C" void kernel_launch(void* const* d_in, const int* in_sizes, int n_in,
                              void* d_out, int out_size, void* d_ws, size_t ws_size,
                              hipStream_t stream) {
  const float* h0        = (const float*)d_in[0];
  const float* h1        = (const float*)d_in[1];
  const float* h2        = (const float*)d_in[2];
  const float* h3        = (const float*)d_in[3];
  const float* proj_w    = (const float*)d_in[4];
  const float* proj_b    = (const float*)d_in[5];
  const float* ctx_w     = (const float*)d_in[6];
  const float* in_proj_w = (const float*)d_in[8];
  const float* in_proj_b = (const float*)d_in[9];
  const float* out_w     = (const float*)d_in[10];
  const float* out_b     = (const float*)d_in[11];
  const float* gate_w    = (const float*)d_in[12];
  const float* gate_b    = (const float*)d_in[13];
  const float* pool_w    = (const float*)d_in[14];
  const float* ln_g      = (const float*)d_in[16];
  const float* ln_b      = (const float*)d_in[17];
  u16* wp = (u16*)d_ws;

  pack_w<<<640, 256, 0, stream>>>(proj_w, in_proj_w, out_w, gate_w, wp);
  fused_k<<<NB / ROWS, 128, 0, stream>>>(h0, h1, h2, h3, wp,
                                         proj_b, ctx_w, in_proj_b, out_b, gate_b,
                                         pool_w, ln_g, ln_b, (float*)d_out);
}

// Round 4
// 309.460 us; speedup vs baseline: 1.3935x; 1.3935x over previous
//
#include <hip/hip_runtime.h>
#include <hip/hip_bf16.h>

typedef unsigned short u16;
typedef unsigned int   u32;
typedef short  short8 __attribute__((ext_vector_type(8)));
typedef float  f32x4  __attribute__((ext_vector_type(4)));

#define NB   65536
#define ROWS 64
#define XP   136
#define OFF1 ((size_t)NB * 128)
#define OFF2 (OFF1 + (size_t)NB * 4)

__device__ __forceinline__ u16 f2bf(float f) {
  __hip_bfloat16 b = __float2bfloat16(f);
  u16 u; __builtin_memcpy(&u, &b, 2); return u;
}
__device__ __forceinline__ float bf2f(u32 bits16) {
  union { u32 u; float f; } v; v.u = bits16 << 16; return v.f;
}
__device__ __forceinline__ u32 pk2(float a, float b) {
  return (u32)f2bf(a) | ((u32)f2bf(b) << 16);
}
__device__ __forceinline__ float unpk(u32 w, int hi) {
  return bf2f(hi ? (w >> 16) : (w & 0xffffu));
}
__device__ __forceinline__ float red16(float v) {
  v += __shfl_xor(v, 1); v += __shfl_xor(v, 2);
  v += __shfl_xor(v, 4); v += __shfl_xor(v, 8);
  return v;
}

// ---------------- weight pre-pack: 10 x [128][128] fp32 -> bf16 MFMA-B-fragment order
// packed[t]: t = w*16384 + nt*2048 + kt*512 + lane*8 + j
//   holds W_w[kt*32 + (lane>>4)*8 + j][nt*16 + (lane&15)]
__global__ void pack_w(const float* __restrict__ proj_w,
                       const float* __restrict__ in_proj_w,
                       const float* __restrict__ out_w,
                       const float* __restrict__ gate_w,
                       u16* __restrict__ wp) {
  int t = blockIdx.x * 256 + threadIdx.x;
  if (t >= 10 * 16384) return;
  int w = t >> 14, i = t & 16383;
  int nt = i >> 11, kt = (i >> 9) & 3, ln = (i >> 3) & 63, j = i & 7;
  int k = kt * 32 + ((ln >> 4) << 3) + j;
  int n = (nt << 4) + (ln & 15);
  float v;
  if (w < 4)       v = proj_w[((size_t)w << 14) + (k << 7) + n];
  else if (w < 7)  v = in_proj_w[k * 384 + ((w - 4) << 7) + n];
  else if (w == 7) v = out_w[(k << 7) + n];
  else             v = gate_w[(((w - 8) << 7) + k) * 128 + n];
  wp[t] = f2bf(v);
}

__device__ __forceinline__ short8 bfrag(const u16* __restrict__ wp, int w, int nt, int kt, int lane) {
  return *(const short8*)(wp + ((size_t)w << 14) + (size_t)((((nt << 2) + kt) << 6) + lane) * 8);
}

struct AF { short8 a[4]; };
__device__ __forceinline__ AF loadA(const u16 (*Ab)[XP], int row, int lgrp) {
  AF r;
  #pragma unroll
  for (int kt = 0; kt < 4; ++kt)
    r.a[kt] = *(const short8*)&Ab[row][kt * 32 + (lgrp << 3)];
  return r;
}
__device__ __forceinline__ f32x4 mmK128(const AF& A, const u16* __restrict__ wp, int w,
                                        int ntg, int lane, float bias) {
  f32x4 acc = {bias, bias, bias, bias};
  #pragma unroll
  for (int kt = 0; kt < 4; ++kt)
    acc = __builtin_amdgcn_mfma_f32_16x16x32_bf16(A.a[kt], bfrag(wp, w, ntg, kt, lane), acc, 0, 0, 0);
  return acc;
}

__global__ __launch_bounds__(512, 2) void fused_k(
    const float* __restrict__ h0, const float* __restrict__ h1,
    const float* __restrict__ h2, const float* __restrict__ h3,
    const u16* __restrict__ wp,
    const float* __restrict__ proj_b, const float* __restrict__ ctx_w,
    const float* __restrict__ in_proj_b, const float* __restrict__ out_b,
    const float* __restrict__ gate_b, const float* __restrict__ pool_w,
    const float* __restrict__ ln_g, const float* __restrict__ ln_b,
    float* __restrict__ out) {
  __shared__ __align__(16) u16 xls[4][ROWS][XP];  // h -> x (stays x to the end)
  __shared__ __align__(16) u16 aux[ROWS][XP];     // context -> o
  __shared__ __align__(16) u16 aob[ROWS][XP];     // attn_out
  __shared__ float lgt[4][2][ROWS];               // ctx logit partials
  __shared__ float scf[4][ROWS][4];               // scores -> attn
  __shared__ float lnr[4][ROWS][2][2];            // LN partials [s][row][wcol][{sum,sq}]
  __shared__ float lgp[ROWS][4][2];               // pool logit partials [row][s][wcol]

  const int tid   = threadIdx.x;
  const int lane  = tid & 63;
  const int wid   = tid >> 6;
  const int wrow  = wid & 3;             // which 16-row tile
  const int wcol  = wid >> 2;            // which 64-col half
  const int wr    = wrow << 4;
  const int nt0   = wcol << 2;
  const int r0    = blockIdx.x * ROWS;
  const int lrow  = lane & 15;
  const int lgrp  = lane >> 4;
  const int crow0 = lgrp << 2;

  const float* hp[4] = {h0, h1, h2, h3};

  // ---- phase 0: load h_s (bf16) into xls
  #pragma unroll
  for (int s = 0; s < 4; ++s) {
    const float* __restrict__ hs = hp[s];
    #pragma unroll
    for (int i = 0; i < 4; ++i) {
      int f4 = i * 512 + tid;
      int row = f4 >> 5, c0 = (f4 & 31) << 2;
      const float4 v = *(const float4*)(hs + ((size_t)(r0 + row) << 7) + c0);
      *(uint2*)&xls[s][row][c0] = make_uint2(pk2(v.x, v.y), pk2(v.z, v.w));
    }
  }
  __syncthreads();                                   // B1
  AF Ah[4];
  #pragma unroll
  for (int s = 0; s < 4; ++s) Ah[s] = loadA(xls[s], wr + lrow, lgrp);
  __syncthreads();                                   // B2

  // ---- phase 1: proj GEMMs (in-place h->x) + ctx logit partials + x C-layout regs
  u32 xcp[4][4][2];
  #pragma unroll
  for (int s = 0; s < 4; ++s) {
    float lp[4] = {0.f, 0.f, 0.f, 0.f};
    #pragma unroll
    for (int nt = 0; nt < 4; ++nt) {
      int ntg = nt0 + nt, n = (ntg << 4) + lrow;
      f32x4 acc = mmK128(Ah[s], wp, s, ntg, lane, proj_b[(s << 7) + n]);
      float cwn = ctx_w[n];
      #pragma unroll
      for (int j = 0; j < 4; ++j) {
        lp[j] += acc[j] * cwn;
        xls[s][wr + crow0 + j][n] = f2bf(acc[j]);
      }
      xcp[s][nt][0] = pk2(acc[0], acc[1]);
      xcp[s][nt][1] = pk2(acc[2], acc[3]);
    }
    #pragma unroll
    for (int j = 0; j < 4; ++j) lp[j] = red16(lp[j]);
    if (lrow == 0) {
      #pragma unroll
      for (int j = 0; j < 4; ++j) lgt[s][wcol][wr + crow0 + j] = lp[j];
    }
  }
  __syncthreads();                                   // B3

  // ---- phase 3: context = sum_s cw[s]*x_s -> aux (ctx softmax computed per-lane)
  #pragma unroll
  for (int i = 0; i < 4; ++i) {
    int e4 = i * 512 + tid;
    int row = e4 >> 5, c0 = (e4 & 31) << 2;
    float l0 = lgt[0][0][row] + lgt[0][1][row];
    float l1 = lgt[1][0][row] + lgt[1][1][row];
    float l2 = lgt[2][0][row] + lgt[2][1][row];
    float l3 = lgt[3][0][row] + lgt[3][1][row];
    float mx = fmaxf(fmaxf(l0, l1), fmaxf(l2, l3));
    float e0 = __expf(l0 - mx), e1 = __expf(l1 - mx), e2 = __expf(l2 - mx), e3 = __expf(l3 - mx);
    float inv = 1.f / (e0 + e1 + e2 + e3);
    float cw[4] = {e0 * inv, e1 * inv, e2 * inv, e3 * inv};
    float a0 = 0, a1 = 0, a2 = 0, a3 = 0;
    #pragma unroll
    for (int s = 0; s < 4; ++s) {
      uint2 d = *(const uint2*)&xls[s][row][c0];
      a0 += cw[s] * unpk(d.x, 0); a1 += cw[s] * unpk(d.x, 1);
      a2 += cw[s] * unpk(d.y, 0); a3 += cw[s] * unpk(d.y, 1);
    }
    *(uint2*)&aux[row][c0] = make_uint2(pk2(a0, a1), pk2(a2, a3));
  }
  __syncthreads();                                   // B4

  // ---- phase 4: q = context @ wq + bq (kept in regs)
  float qf[4][4];
  {
    AF Ac = loadA(aux, wr + lrow, lgrp);
    #pragma unroll
    for (int nt = 0; nt < 4; ++nt) {
      int ntg = nt0 + nt, n = (ntg << 4) + lrow;
      f32x4 acc = mmK128(Ac, wp, 4, ntg, lane, in_proj_b[n]);
      #pragma unroll
      for (int j = 0; j < 4; ++j) qf[nt][j] = acc[j];
    }
  }

  // ---- phase 5: K GEMM (s-inner, B-frag shared) + scores
  AF Ax[4];
  #pragma unroll
  for (int s = 0; s < 4; ++s) Ax[s] = loadA(xls[s], wr + lrow, lgrp);
  {
    float sc[4][4][2] = {};
    #pragma unroll
    for (int nt = 0; nt < 4; ++nt) {
      int ntg = nt0 + nt, n = (ntg << 4) + lrow;
      const int hh = (ntg >> 1) & 1;
      float bk = in_proj_b[128 + n];
      f32x4 ak[4];
      #pragma unroll
      for (int s = 0; s < 4; ++s) ak[s] = (f32x4){bk, bk, bk, bk};
      #pragma unroll
      for (int kt = 0; kt < 4; ++kt) {
        short8 bf = bfrag(wp, 5, ntg, kt, lane);
        #pragma unroll
        for (int s = 0; s < 4; ++s)
          ak[s] = __builtin_amdgcn_mfma_f32_16x16x32_bf16(Ax[s].a[kt], bf, ak[s], 0, 0, 0);
      }
      #pragma unroll
      for (int s = 0; s < 4; ++s)
        #pragma unroll
        for (int j = 0; j < 4; ++j)
          sc[s][j][hh] += ak[s][j] * qf[nt][j];
    }
    #pragma unroll
    for (int s = 0; s < 4; ++s)
      #pragma unroll
      for (int j = 0; j < 4; ++j)
        #pragma unroll
        for (int hh = 0; hh < 2; ++hh)
          sc[s][j][hh] = red16(sc[s][j][hh]);
    #pragma unroll
    for (int s = 0; s < 4; ++s)
      #pragma unroll
      for (int hh = 0; hh < 2; ++hh) {
        int h = (wcol << 1) + hh;
        if (lrow == h) {
          #pragma unroll
          for (int j = 0; j < 4; ++j) scf[s][wr + crow0 + j][h] = sc[s][j][hh];
        }
      }
  }
  __syncthreads();                                   // B5

  // ---- phase 5b: attn softmax over s
  if (tid < 256) {
    int row = tid >> 2, h = tid & 3;
    const float scale = 0.17677669529663687f;  // 1/sqrt(32)
    float l0 = scf[0][row][h] * scale, l1 = scf[1][row][h] * scale;
    float l2 = scf[2][row][h] * scale, l3 = scf[3][row][h] * scale;
    float mx = fmaxf(fmaxf(l0, l1), fmaxf(l2, l3));
    float e0 = __expf(l0 - mx), e1 = __expf(l1 - mx), e2 = __expf(l2 - mx), e3 = __expf(l3 - mx);
    float inv = 1.f / (e0 + e1 + e2 + e3);
    scf[0][row][h] = e0 * inv; scf[1][row][h] = e1 * inv;
    scf[2][row][h] = e2 * inv; scf[3][row][h] = e3 * inv;
  }
  __syncthreads();                                   // B6
  if (tid < 256) {
    int row = tid >> 2, s = tid & 3;
    float m = 0.25f * (scf[s][row][0] + scf[s][row][1] + scf[s][row][2] + scf[s][row][3]);
    out[OFF1 + ((size_t)r0 << 2) + tid] = m;
  }

  // ---- phase 6: V GEMM (s-inner) + o = sum_s attn*v -> aux
  {
    float aw[4][4][2];
    #pragma unroll
    for (int s = 0; s < 4; ++s)
      #pragma unroll
      for (int j = 0; j < 4; ++j)
        #pragma unroll
        for (int hh = 0; hh < 2; ++hh)
          aw[s][j][hh] = scf[s][wr + crow0 + j][(wcol << 1) + hh];
    float oa[4][4] = {};
    #pragma unroll
    for (int nt = 0; nt < 4; ++nt) {
      int ntg = nt0 + nt, n = (ntg << 4) + lrow;
      const int hh = (ntg >> 1) & 1;
      float bv = in_proj_b[256 + n];
      f32x4 av[4];
      #pragma unroll
      for (int s = 0; s < 4; ++s) av[s] = (f32x4){bv, bv, bv, bv};
      #pragma unroll
      for (int kt = 0; kt < 4; ++kt) {
        short8 bf = bfrag(wp, 6, ntg, kt, lane);
        #pragma unroll
        for (int s = 0; s < 4; ++s)
          av[s] = __builtin_amdgcn_mfma_f32_16x16x32_bf16(Ax[s].a[kt], bf, av[s], 0, 0, 0);
      }
      #pragma unroll
      for (int s = 0; s < 4; ++s)
        #pragma unroll
        for (int j = 0; j < 4; ++j)
          oa[nt][j] += aw[s][j][hh] * av[s][j];
    }
    #pragma unroll
    for (int nt = 0; nt < 4; ++nt) {
      int n = ((nt0 + nt) << 4) + lrow;
      #pragma unroll
      for (int j = 0; j < 4; ++j) aux[wr + crow0 + j][n] = f2bf(oa[nt][j]);
    }
  }
  __syncthreads();                                   // B7

  // ---- phase 7: attn_out = o @ out_w + out_b
  float aoreg[4][4];
  {
    AF Ao = loadA(aux, wr + lrow, lgrp);
    #pragma unroll
    for (int nt = 0; nt < 4; ++nt) {
      int ntg = nt0 + nt, n = (ntg << 4) + lrow;
      f32x4 acc = mmK128(Ao, wp, 7, ntg, lane, out_b[n]);
      #pragma unroll
      for (int j = 0; j < 4; ++j) {
        aoreg[nt][j] = acc[j];
        aob[wr + crow0 + j][n] = f2bf(acc[j]);
      }
    }
  }
  __syncthreads();                                   // B8

  // ---- phase 8a: gate GEMM + sigmoid (g out) + fuse + LN partials (all s, one barrier)
  u32 frp[4][4][2];
  {
    AF Aa = loadA(aob, wr + lrow, lgrp);
    float gbv[4];
    #pragma unroll
    for (int nt = 0; nt < 4; ++nt) gbv[nt] = gate_b[((nt0 + nt) << 4) + lrow];
    #pragma unroll
    for (int s = 0; s < 4; ++s) {
      float sm[4] = {0, 0, 0, 0}, sq[4] = {0, 0, 0, 0};
      #pragma unroll
      for (int nt = 0; nt < 4; ++nt) {
        int ntg = nt0 + nt, n = (ntg << 4) + lrow;
        f32x4 acc = {gbv[nt], gbv[nt], gbv[nt], gbv[nt]};
        #pragma unroll
        for (int kt = 0; kt < 4; ++kt)
          acc = __builtin_amdgcn_mfma_f32_16x16x32_bf16(Ax[s].a[kt], bfrag(wp, 8, ntg, kt, lane), acc, 0, 0, 0);
        #pragma unroll
        for (int kt = 0; kt < 4; ++kt)
          acc = __builtin_amdgcn_mfma_f32_16x16x32_bf16(Aa.a[kt], bfrag(wp, 9, ntg, kt, lane), acc, 0, 0, 0);
        float f[4];
        #pragma unroll
        for (int j = 0; j < 4; ++j) {
          float g = 1.f / (1.f + __expf(-acc[j]));
          out[OFF2 + (((size_t)(r0 + wr + crow0 + j) << 2) + s) * 128 + n] = g;
          float xv = unpk(xcp[s][nt][j >> 1], j & 1);
          f[j] = g * aoreg[nt][j] + (1.f - g) * xv;
          sm[j] += f[j];
          sq[j] += f[j] * f[j];
        }
        frp[s][nt][0] = pk2(f[0], f[1]);
        frp[s][nt][1] = pk2(f[2], f[3]);
      }
      #pragma unroll
      for (int j = 0; j < 4; ++j) { sm[j] = red16(sm[j]); sq[j] = red16(sq[j]); }
      if (lrow == 0) {
        #pragma unroll
        for (int j = 0; j < 4; ++j) {
          lnr[s][wr + crow0 + j][wcol][0] = sm[j];
          lnr[s][wr + crow0 + j][wcol][1] = sq[j];
        }
      }
    }
  }
  __syncthreads();                                   // B9

  // ---- phase 8b: LN finalize + pool logit partials
  float lng[4], lnb[4], pwv[4];
  #pragma unroll
  for (int nt = 0; nt < 4; ++nt) {
    int n = ((nt0 + nt) << 4) + lrow;
    lng[nt] = ln_g[n]; lnb[nt] = ln_b[n]; pwv[nt] = pool_w[n];
  }
  float mean_[4][4], rstd_[4][4];
  #pragma unroll
  for (int s = 0; s < 4; ++s) {
    float pp[4] = {0, 0, 0, 0};
    #pragma unroll
    for (int j = 0; j < 4; ++j) {
      float4 t = *(const float4*)&lnr[s][wr + crow0 + j][0][0];
      float mean = (t.x + t.z) * 0.0078125f;
      float var  = (t.y + t.w) * 0.0078125f - mean * mean;
      float rstd = rsqrtf(var + 1e-5f);
      mean_[s][j] = mean; rstd_[s][j] = rstd;
      #pragma unroll
      for (int nt = 0; nt < 4; ++nt) {
        float f = unpk(frp[s][nt][j >> 1], j & 1);
        float fn = (f - mean) * rstd * lng[nt] + lnb[nt];
        pp[j] += fn * pwv[nt];
      }
    }
    #pragma unroll
    for (int j = 0; j < 4; ++j) pp[j] = red16(pp[j]);
    if (lrow == 0) {
      #pragma unroll
      for (int j = 0; j < 4; ++j) lgp[wr + crow0 + j][s][wcol] = pp[j];
    }
  }
  __syncthreads();                                   // B10

  // ---- phase 9: pool softmax per-lane + pooled output
  #pragma unroll
  for (int j = 0; j < 4; ++j) {
    int row = wr + crow0 + j;
    float4 ta = *(const float4*)&lgp[row][0][0];
    float4 tb = *(const float4*)&lgp[row][2][0];
    float l0 = ta.x + ta.y, l1 = ta.z + ta.w, l2 = tb.x + tb.y, l3 = tb.z + tb.w;
    float mx = fmaxf(fmaxf(l0, l1), fmaxf(l2, l3));
    float e0 = __expf(l0 - mx), e1 = __expf(l1 - mx), e2 = __expf(l2 - mx), e3 = __expf(l3 - mx);
    float inv = 1.f / (e0 + e1 + e2 + e3);
    float pw[4] = {e0 * inv, e1 * inv, e2 * inv, e3 * inv};
    #pragma unroll
    for (int nt = 0; nt < 4; ++nt) {
      int n = ((nt0 + nt) << 4) + lrow;
      float acc = 0.f;
      #pragma unroll
      for (int s = 0; s < 4; ++s) {
        float f = unpk(frp[s][nt][j >> 1], j & 1);
        float fn = (f - mean_[s][j]) * rstd_[s][j] * lng[nt] + lnb[nt];
        acc += pw[s] * fn;
      }
      out[((size_t)(r0 + row) << 7) + n] = acc;
    }
  }
}

extern "C" void kernel_launch(void* const* d_in, const int* in_sizes, int n_in,
                              void* d_out, int out_size, void* d_ws, size_t ws_size,
                              hipStream_t stream) {
  const float* h0        = (const float*)d_in[0];
  const float* h1        = (const float*)d_in[1];
  const float* h2        = (const float*)d_in[2];
  const float* h3        = (const float*)d_in[3];
  const float* proj_w    = (const float*)d_in[4];
  const float* proj_b    = (const float*)d_in[5];
  const float* ctx_w     = (const float*)d_in[6];
  const float* in_proj_w = (const float*)d_in[8];
  const float* in_proj_b = (const float*)d_in[9];
  const float* out_w     = (const float*)d_in[10];
  const float* out_b     = (const float*)d_in[11];
  const float* gate_w    = (const float*)d_in[12];
  const float* gate_b    = (const float*)d_in[13];
  const float* pool_w    = (const float*)d_in[14];
  const float* ln_g      = (const float*)d_in[16];
  const float* ln_b      = (const float*)d_in[17];
  u16* wp = (u16*)d_ws;

  pack_w<<<640, 256, 0, stream>>>(proj_w, in_proj_w, out_w, gate_w, wp);
  fused_k<<<NB / ROWS, 512, 0, stream>>>(h0, h1, h2, h3, wp,
                                         proj_b, ctx_w, in_proj_b, out_b, gate_b,
                                         pool_w, ln_g, ln_b, (float*)d_out);
}

// Round 7
// 208.155 us; speedup vs baseline: 2.0717x; 1.4867x over previous
//
#include <hip/hip_runtime.h>
#include <hip/hip_bf16.h>

typedef unsigned short u16;
typedef unsigned int   u32;
typedef short  short8 __attribute__((ext_vector_type(8)));
typedef float  f32x4  __attribute__((ext_vector_type(4)));

#define NB    65536
#define XP    132
#define OFF1  ((size_t)NB * 128)
#define OFF2  (OFF1 + (size_t)NB * 4)

__device__ __forceinline__ u16 f2bf(float f) {
  __hip_bfloat16 b = __float2bfloat16(f);
  u16 u; __builtin_memcpy(&u, &b, 2); return u;
}
__device__ __forceinline__ float bf2f(u32 bits16) {
  union { u32 u; float f; } v; v.u = bits16 << 16; return v.f;
}
__device__ __forceinline__ float red16(float v) {
  v += __shfl_xor(v, 1); v += __shfl_xor(v, 2);
  v += __shfl_xor(v, 4); v += __shfl_xor(v, 8);
  return v;
}
// completes all outstanding LDS ops; compiler memory barrier (no HW barrier)
__device__ __forceinline__ void lds_fence() {
  asm volatile("s_waitcnt lgkmcnt(0)" ::: "memory");
}

// ---------------- weight pre-pack: 10 x [128][128] fp32 -> bf16 MFMA-B-fragment order
// packed[t]: t = w*16384 + nt*2048 + kt*512 + lane*8 + j
//   holds W_w[kt*32 + (lane>>4)*8 + j][nt*16 + (lane&15)]
__global__ void pack_w(const float* __restrict__ proj_w,
                       const float* __restrict__ in_proj_w,
                       const float* __restrict__ out_w,
                       const float* __restrict__ gate_w,
                       u16* __restrict__ wp) {
  int t = blockIdx.x * 256 + threadIdx.x;
  if (t >= 10 * 16384) return;
  int w = t >> 14, i = t & 16383;
  int nt = i >> 11, kt = (i >> 9) & 3, ln = (i >> 3) & 63, j = i & 7;
  int k = kt * 32 + ((ln >> 4) << 3) + j;
  int n = (nt << 4) + (ln & 15);
  float v;
  if (w < 4)       v = proj_w[((size_t)w << 14) + (k << 7) + n];
  else if (w < 7)  v = in_proj_w[k * 384 + ((w - 4) << 7) + n];
  else if (w == 7) v = out_w[(k << 7) + n];
  else             v = gate_w[(((w - 8) << 7) + k) * 128 + n];
  wp[t] = f2bf(v);
}

__device__ __forceinline__ short8 bfrag(const u16* __restrict__ wp, int w, int nt, int kt, int lane) {
  return *(const short8*)(wp + ((size_t)w << 14) + (size_t)((((nt << 2) + kt) << 6) + lane) * 8);
}

struct AF { short8 a[4]; };
__device__ __forceinline__ AF loadA(const u16 (*Ab)[XP], int row, int lgrp) {
  AF r;
  #pragma unroll
  for (int kt = 0; kt < 4; ++kt)
    r.a[kt] = *(const short8*)&Ab[row][kt * 32 + (lgrp << 3)];
  return r;
}
__device__ __forceinline__ f32x4 mmK128(const AF& A, const u16* __restrict__ wp, int w,
                                        int ntg, int lane, float bias) {
  f32x4 acc = {bias, bias, bias, bias};
  #pragma unroll
  for (int kt = 0; kt < 4; ++kt)
    acc = __builtin_amdgcn_mfma_f32_16x16x32_bf16(A.a[kt], bfrag(wp, w, ntg, kt, lane), acc, 0, 0, 0);
  return acc;
}

// One wave (64 threads) per 16-row tile. NO __syncthreads anywhere.
__global__ __launch_bounds__(64, 2) void fused_k(
    const float* __restrict__ h0, const float* __restrict__ h1,
    const float* __restrict__ h2, const float* __restrict__ h3,
    const u16* __restrict__ wp,
    const float* __restrict__ proj_b, const float* __restrict__ ctx_w,
    const float* __restrict__ in_proj_b, const float* __restrict__ out_b,
    const float* __restrict__ gate_b, const float* __restrict__ pool_w,
    const float* __restrict__ ln_g, const float* __restrict__ ln_b,
    float* __restrict__ out) {
  __shared__ __align__(16) u16 xls[4][16][XP];  // x_s, overwritten by fused f_s
  __shared__ __align__(16) u16 scr[16][XP];     // context / o / attn_out transpose scratch

  const int lane  = threadIdx.x;     // 0..63
  const int lrow  = lane & 15;       // A-row / C-col-within-chunk
  const int lgrp  = lane >> 4;
  const int crow0 = lgrp << 2;       // C rows 4*lgrp + j
  const size_t r0w = (size_t)blockIdx.x * 16;

  const float* hp[4] = {h0, h1, h2, h3};

  // ---- P0: per source: h A-frags direct from global, proj GEMM -> xls, ctx logit partials
  float ctxl[4][4];
  #pragma unroll
  for (int s = 0; s < 4; ++s) {
    const float* __restrict__ hb = hp[s] + ((r0w + lrow) << 7) + (lgrp << 3);
    AF Ah;
    #pragma unroll
    for (int kt = 0; kt < 4; ++kt) {
      float4 va = *(const float4*)(hb + kt * 32);
      float4 vb = *(const float4*)(hb + kt * 32 + 4);
      short8 v;
      v[0] = (short)f2bf(va.x); v[1] = (short)f2bf(va.y);
      v[2] = (short)f2bf(va.z); v[3] = (short)f2bf(va.w);
      v[4] = (short)f2bf(vb.x); v[5] = (short)f2bf(vb.y);
      v[6] = (short)f2bf(vb.z); v[7] = (short)f2bf(vb.w);
      Ah.a[kt] = v;
    }
    float lp[4] = {0.f, 0.f, 0.f, 0.f};
    #pragma unroll
    for (int nt = 0; nt < 8; ++nt) {
      int n = (nt << 4) + lrow;
      f32x4 acc = mmK128(Ah, wp, s, nt, lane, proj_b[(s << 7) + n]);
      float cwn = ctx_w[n];
      #pragma unroll
      for (int j = 0; j < 4; ++j) {
        lp[j] += acc[j] * cwn;
        xls[s][crow0 + j][n] = f2bf(acc[j]);
      }
    }
    #pragma unroll
    for (int j = 0; j < 4; ++j) ctxl[s][j] = red16(lp[j]);
  }

  // ---- P1: ctx softmax per row (per-lane) + context -> scr
  float cw[4][4];
  #pragma unroll
  for (int j = 0; j < 4; ++j) {
    float l0 = ctxl[0][j], l1 = ctxl[1][j], l2 = ctxl[2][j], l3 = ctxl[3][j];
    float mx = fmaxf(fmaxf(l0, l1), fmaxf(l2, l3));
    float e0 = __expf(l0 - mx), e1 = __expf(l1 - mx), e2 = __expf(l2 - mx), e3 = __expf(l3 - mx);
    float inv = 1.f / (e0 + e1 + e2 + e3);
    cw[0][j] = e0 * inv; cw[1][j] = e1 * inv; cw[2][j] = e2 * inv; cw[3][j] = e3 * inv;
  }
  #pragma unroll
  for (int nt = 0; nt < 8; ++nt) {
    int n = (nt << 4) + lrow;
    #pragma unroll
    for (int j = 0; j < 4; ++j) {
      float v = cw[0][j] * bf2f((u32)xls[0][crow0 + j][n])
              + cw[1][j] * bf2f((u32)xls[1][crow0 + j][n])
              + cw[2][j] * bf2f((u32)xls[2][crow0 + j][n])
              + cw[3][j] * bf2f((u32)xls[3][crow0 + j][n]);
      scr[crow0 + j][n] = f2bf(v);
    }
  }
  lds_fence();
  AF Ac = loadA(scr, lrow, lgrp);

  // ---- P2: q = context @ wq + bq (C-layout regs)
  float qf[8][4];
  #pragma unroll
  for (int nt = 0; nt < 8; ++nt) {
    int n = (nt << 4) + lrow;
    f32x4 acc = mmK128(Ac, wp, 4, nt, lane, in_proj_b[n]);
    #pragma unroll
    for (int j = 0; j < 4; ++j) qf[nt][j] = acc[j];
  }

  // ---- P3: K GEMM (s-inner, B shared) + scores
  lds_fence();
  AF Axs[4];
  #pragma unroll
  for (int s = 0; s < 4; ++s) Axs[s] = loadA(xls[s], lrow, lgrp);
  float sc[4][4][4] = {};   // [s][j][h]
  #pragma unroll
  for (int nt = 0; nt < 8; ++nt) {
    int n = (nt << 4) + lrow;
    const int h = nt >> 1;
    float bk = in_proj_b[128 + n];
    f32x4 ak[4];
    #pragma unroll
    for (int s = 0; s < 4; ++s) ak[s] = (f32x4){bk, bk, bk, bk};
    #pragma unroll
    for (int kt = 0; kt < 4; ++kt) {
      short8 bf = bfrag(wp, 5, nt, kt, lane);
      #pragma unroll
      for (int s = 0; s < 4; ++s)
        ak[s] = __builtin_amdgcn_mfma_f32_16x16x32_bf16(Axs[s].a[kt], bf, ak[s], 0, 0, 0);
    }
    #pragma unroll
    for (int s = 0; s < 4; ++s)
      #pragma unroll
      for (int j = 0; j < 4; ++j)
        sc[s][j][h] += ak[s][j] * qf[nt][j];
  }
  #pragma unroll
  for (int s = 0; s < 4; ++s)
    #pragma unroll
    for (int j = 0; j < 4; ++j)
      #pragma unroll
      for (int h = 0; h < 4; ++h)
        sc[s][j][h] = red16(sc[s][j][h]);

  // ---- P4: attn softmax per lane + attn_weights out
  float aw[4][4][4];
  #pragma unroll
  for (int j = 0; j < 4; ++j)
    #pragma unroll
    for (int h = 0; h < 4; ++h) {
      const float scale = 0.17677669529663687f;  // 1/sqrt(32)
      float l0 = sc[0][j][h] * scale, l1 = sc[1][j][h] * scale;
      float l2 = sc[2][j][h] * scale, l3 = sc[3][j][h] * scale;
      float mx = fmaxf(fmaxf(l0, l1), fmaxf(l2, l3));
      float e0 = __expf(l0 - mx), e1 = __expf(l1 - mx), e2 = __expf(l2 - mx), e3 = __expf(l3 - mx);
      float inv = 1.f / (e0 + e1 + e2 + e3);
      aw[0][j][h] = e0 * inv; aw[1][j][h] = e1 * inv;
      aw[2][j][h] = e2 * inv; aw[3][j][h] = e3 * inv;
    }
  {
    float* awp = (float*)scr;   // scr dead (Ac in regs)
    if (lrow == 0) {
      #pragma unroll
      for (int s = 0; s < 4; ++s)
        #pragma unroll
        for (int j = 0; j < 4; ++j)
          awp[((crow0 + j) << 2) + s] =
            0.25f * (aw[s][j][0] + aw[s][j][1] + aw[s][j][2] + aw[s][j][3]);
    }
    lds_fence();
    out[OFF1 + (r0w << 2) + lane] = awp[lane];
  }

  // ---- P5: V GEMM (s-inner) + o -> scr
  {
    float oa[8][4] = {};
    #pragma unroll
    for (int nt = 0; nt < 8; ++nt) {
      int n = (nt << 4) + lrow;
      const int h = nt >> 1;
      float bv = in_proj_b[256 + n];
      f32x4 av[4];
      #pragma unroll
      for (int s = 0; s < 4; ++s) av[s] = (f32x4){bv, bv, bv, bv};
      #pragma unroll
      for (int kt = 0; kt < 4; ++kt) {
        short8 bf = bfrag(wp, 6, nt, kt, lane);
        #pragma unroll
        for (int s = 0; s < 4; ++s)
          av[s] = __builtin_amdgcn_mfma_f32_16x16x32_bf16(Axs[s].a[kt], bf, av[s], 0, 0, 0);
      }
      #pragma unroll
      for (int s = 0; s < 4; ++s)
        #pragma unroll
        for (int j = 0; j < 4; ++j)
          oa[nt][j] += aw[s][j][h] * av[s][j];
    }
    #pragma unroll
    for (int nt = 0; nt < 8; ++nt) {
      int n = (nt << 4) + lrow;
      #pragma unroll
      for (int j = 0; j < 4; ++j) scr[crow0 + j][n] = f2bf(oa[nt][j]);
    }
  }
  lds_fence();
  AF Ao = loadA(scr, lrow, lgrp);

  // ---- P6: attn_out = o @ out_w + out_b; fp32 C-layout regs + scr for Aa frags
  float aoreg[8][4];
  #pragma unroll
  for (int nt = 0; nt < 8; ++nt) {
    int n = (nt << 4) + lrow;
    f32x4 acc = mmK128(Ao, wp, 7, nt, lane, out_b[n]);
    #pragma unroll
    for (int j = 0; j < 4; ++j) {
      scr[crow0 + j][n] = f2bf(acc[j]);
      aoreg[nt][j] = acc[j];
    }
  }
  lds_fence();
  AF Aa = loadA(scr, lrow, lgrp);

  // ---- P7: gate. aacc = gate_b + ao @ W9 kept FP32, then per-s + x @ W8 (fp32 chain)
  f32x4 aacc[8];
  #pragma unroll
  for (int nt = 0; nt < 8; ++nt) {
    int n = (nt << 4) + lrow;
    float gb = gate_b[n];
    f32x4 t = {gb, gb, gb, gb};
    #pragma unroll
    for (int kt = 0; kt < 4; ++kt)
      t = __builtin_amdgcn_mfma_f32_16x16x32_bf16(Aa.a[kt], bfrag(wp, 9, nt, kt, lane), t, 0, 0, 0);
    aacc[nt] = t;
  }
  float sm[4][4] = {}, sq[4][4] = {};
  #pragma unroll
  for (int nt = 0; nt < 8; ++nt) {
    int n = (nt << 4) + lrow;
    short8 bf8[4];
    #pragma unroll
    for (int kt = 0; kt < 4; ++kt) bf8[kt] = bfrag(wp, 8, nt, kt, lane);
    #pragma unroll
    for (int s = 0; s < 4; ++s) {
      f32x4 acc = aacc[nt];
      #pragma unroll
      for (int kt = 0; kt < 4; ++kt)
        acc = __builtin_amdgcn_mfma_f32_16x16x32_bf16(Axs[s].a[kt], bf8[kt], acc, 0, 0, 0);
      #pragma unroll
      for (int j = 0; j < 4; ++j) {
        float g = 1.f / (1.f + __expf(-acc[j]));
        out[OFF2 + (((r0w + crow0 + j) << 2) + s) * 128 + n] = g;
        float xv = bf2f((u32)xls[s][crow0 + j][n]);
        float f = g * aoreg[nt][j] + (1.f - g) * xv;
        sm[s][j] += f;
        sq[s][j] += f * f;
        xls[s][crow0 + j][n] = f2bf(f);   // overwrite x with fused (same lane, same addr)
      }
    }
  }
  float mean_[4][4], rstd_[4][4];
  #pragma unroll
  for (int s = 0; s < 4; ++s)
    #pragma unroll
    for (int j = 0; j < 4; ++j) {
      float ts = red16(sm[s][j]);
      float tq = red16(sq[s][j]);
      float mean = ts * 0.0078125f;
      float var  = tq * 0.0078125f - mean * mean;
      mean_[s][j] = mean;
      rstd_[s][j] = rsqrtf(var + 1e-5f);
    }

  // ---- P8: pool logits (fp32 fn from bf16 f) + softmax + pooled out
  float lngv[8], lnbv[8], pwvv[8];
  #pragma unroll
  for (int nt = 0; nt < 8; ++nt) {
    int n = (nt << 4) + lrow;
    lngv[nt] = ln_g[n]; lnbv[nt] = ln_b[n]; pwvv[nt] = pool_w[n];
  }
  float pp[4][4] = {};
  #pragma unroll
  for (int nt = 0; nt < 8; ++nt) {
    int n = (nt << 4) + lrow;
    #pragma unroll
    for (int s = 0; s < 4; ++s)
      #pragma unroll
      for (int j = 0; j < 4; ++j) {
        float f  = bf2f((u32)xls[s][crow0 + j][n]);
        float fn = (f - mean_[s][j]) * rstd_[s][j] * lngv[nt] + lnbv[nt];
        pp[s][j] += fn * pwvv[nt];
      }
  }
  float pw[4][4];
  #pragma unroll
  for (int j = 0; j < 4; ++j) {
    float l0 = red16(pp[0][j]), l1 = red16(pp[1][j]);
    float l2 = red16(pp[2][j]), l3 = red16(pp[3][j]);
    float mx = fmaxf(fmaxf(l0, l1), fmaxf(l2, l3));
    float e0 = __expf(l0 - mx), e1 = __expf(l1 - mx), e2 = __expf(l2 - mx), e3 = __expf(l3 - mx);
    float inv = 1.f / (e0 + e1 + e2 + e3);
    pw[0][j] = e0 * inv; pw[1][j] = e1 * inv; pw[2][j] = e2 * inv; pw[3][j] = e3 * inv;
  }
  #pragma unroll
  for (int nt = 0; nt < 8; ++nt) {
    int n = (nt << 4) + lrow;
    #pragma unroll
    for (int j = 0; j < 4; ++j) {
      float acc = 0.f;
      #pragma unroll
      for (int s = 0; s < 4; ++s) {
        float f  = bf2f((u32)xls[s][crow0 + j][n]);
        float fn = (f - mean_[s][j]) * rstd_[s][j] * lngv[nt] + lnbv[nt];
        acc += pw[s][j] * fn;
      }
      out[((r0w + crow0 + j) << 7) + n] = acc;
    }
  }
}

extern "C" void kernel_launch(void* const* d_in, const int* in_sizes, int n_in,
                              void* d_out, int out_size, void* d_ws, size_t ws_size,
                              hipStream_t stream) {
  const float* h0        = (const float*)d_in[0];
  const float* h1        = (const float*)d_in[1];
  const float* h2        = (const float*)d_in[2];
  const float* h3        = (const float*)d_in[3];
  const float* proj_w    = (const float*)d_in[4];
  const float* proj_b    = (const float*)d_in[5];
  const float* ctx_w     = (const float*)d_in[6];
  const float* in_proj_w = (const float*)d_in[8];
  const float* in_proj_b = (const float*)d_in[9];
  const float* out_w     = (const float*)d_in[10];
  const float* out_b     = (const float*)d_in[11];
  const float* gate_w    = (const float*)d_in[12];
  const float* gate_b    = (const float*)d_in[13];
  const float* pool_w    = (const float*)d_in[14];
  const float* ln_g      = (const float*)d_in[16];
  const float* ln_b      = (const float*)d_in[17];
  u16* wp = (u16*)d_ws;

  pack_w<<<640, 256, 0, stream>>>(proj_w, in_proj_w, out_w, gate_w, wp);
  fused_k<<<NB / 16, 64, 0, stream>>>(h0, h1, h2, h3, wp,
                                      proj_b, ctx_w, in_proj_b, out_b, gate_b,
                                      pool_w, ln_g, ln_b, (float*)d_out);
}